// Round 1
// baseline (22457.996 us; speedup 1.0000x reference)
//
#include <hip/hip_runtime.h>
#include <stdint.h>

#define Bb 64
#define Tt 512
#define Ii 1024
#define Uu 1024
#define KK 2048
#define NN 3072

typedef __attribute__((ext_vector_type(8))) short short8;
typedef __attribute__((ext_vector_type(4))) float f32x4;

__device__ __forceinline__ unsigned short f2bf(float f) {
    union { float f; unsigned u; } v; v.f = f;
    return (unsigned short)((v.u + 0x7FFFu + ((v.u >> 16) & 1u)) >> 16);
}

// block reduce of two values; valid result only on thread 0
__device__ __forceinline__ float2 block_reduce2(float s, float s2) {
    int lane = threadIdx.x & 63, wv = threadIdx.x >> 6;
    #pragma unroll
    for (int m = 32; m > 0; m >>= 1) {
        s  += __shfl_down(s,  m, 64);
        s2 += __shfl_down(s2, m, 64);
    }
    __shared__ float sh[4][2];
    if (lane == 0) { sh[wv][0] = s; sh[wv][1] = s2; }
    __syncthreads();
    float a = 0.f, b = 0.f;
    if (threadIdx.x == 0) {
        #pragma unroll
        for (int i = 0; i < 4; ++i) { a += sh[i][0]; b += sh[i][1]; }
    }
    return make_float2(a, b);
}

// W (3072x2048 f32) -> Wsc bf16 (scale_j * W[n][j]), S_n = sum_j scale_j*W, bias2_n = b_n + sum_j lnb_j*W
__global__ __launch_bounds__(256) void k_prep_w(
        const float* __restrict__ W, const float* __restrict__ bvec,
        const float* __restrict__ lns, const float* __restrict__ lnb,
        unsigned short* __restrict__ Wsc, float* __restrict__ S, float* __restrict__ bias2) {
    int n = blockIdx.x;
    const float* wr = W + (size_t)n * KK;
    unsigned short* ww = Wsc + (size_t)n * KK;
    float s = 0.f, bb = 0.f;
    for (int j = threadIdx.x; j < KK; j += 256) {
        float w  = wr[j];
        float ws = w * lns[j];
        ww[j] = f2bf(ws);
        s  += ws;
        bb += w * lnb[j];
    }
    float2 tot = block_reduce2(s, bb);
    if (threadIdx.x == 0) { S[n] = tot.x; bias2[n] = bvec[n] + tot.y; }
}

// inputs (B,T,I) f32 -> bf16 copy + per-row (sum, sumsq)
__global__ __launch_bounds__(256) void k_prep_x(
        const float* __restrict__ X, unsigned short* __restrict__ xbf,
        float2* __restrict__ xsums) {
    size_t row = blockIdx.x;
    const float* xr = X + row * Ii;
    unsigned short* xw = xbf + row * Ii;
    float s = 0.f, s2 = 0.f;
    for (int j = threadIdx.x; j < Ii; j += 256) {
        float v = xr[j];
        xw[j] = f2bf(v);
        s += v; s2 += v * v;
    }
    float2 tot = block_reduce2(s, s2);
    if (threadIdx.x == 0) xsums[row] = tot;
}

// initial carry: apply resets[:,0] mask, write f32+bf16 state, write csums slot 0
__global__ __launch_bounds__(256) void k_prep_c(
        const float* __restrict__ carry, const int* __restrict__ resets,
        float* __restrict__ cf, unsigned short* __restrict__ cb,
        float* __restrict__ csums) {
    int b = blockIdx.x;
    int rr = resets[(size_t)b * Tt];
    float s = 0.f, s2 = 0.f;
    for (int u = threadIdx.x; u < Uu; u += 256) {
        float v = rr ? 0.f : carry[(size_t)b * Uu + u];
        cf[(size_t)b * Uu + u] = v;
        cb[(size_t)b * Uu + u] = f2bf(v);
        s += v; s2 += v * v;
    }
    float2 tot = block_reduce2(s, s2);
    if (threadIdx.x == 0) { csums[2 * b] = tot.x; csums[2 * b + 1] = tot.y; }
}

// one GRU time step: GEMM (64 x 2048) @ Wsc^T for this block's 16 u-columns x 3 gates,
// then LN-linearized epilogue + gates + state update + next-step sums.
__global__ __launch_bounds__(256) void k_step(
        int t,
        const unsigned short* __restrict__ xbf,
        const unsigned short* __restrict__ Wsc,
        const float* __restrict__ S,
        const float* __restrict__ bias2,
        const float2* __restrict__ xsums,
        const int* __restrict__ resets,
        const float* __restrict__ cf_cur,
        const unsigned short* __restrict__ cb_cur,
        float* __restrict__ cf_nxt,
        unsigned short* __restrict__ cb_nxt,
        float* __restrict__ csums,
        float* __restrict__ out) {
    const int u0   = blockIdx.x * 16;
    const int wv   = threadIdx.x >> 6;
    const int lane = threadIdx.x & 63;
    const int lrow = lane & 15;   // A row within wave tile; also B col (u offset)
    const int lkg  = lane >> 4;   // k-group

    const int arow = wv * 16 + lrow;  // batch row for A fragment
    const unsigned short* aptr_c = cb_cur + (size_t)arow * Uu;
    const unsigned short* aptr_x = xbf + ((size_t)arow * Tt + t) * Ii;
    const unsigned short* b0p = Wsc + (size_t)(0 * Uu + u0 + lrow) * KK;
    const unsigned short* b1p = Wsc + (size_t)(1 * Uu + u0 + lrow) * KK;
    const unsigned short* b2p = Wsc + (size_t)(2 * Uu + u0 + lrow) * KK;

    f32x4 acc0 = {0.f, 0.f, 0.f, 0.f};
    f32x4 acc1 = acc0, acc2 = acc0;

    const int kfb = lkg * 8;
    // carry half of K (j in [0,1024))
    #pragma unroll 4
    for (int k0 = 0; k0 < 1024; k0 += 32) {
        int kf = k0 + kfb;
        short8 a  = *(const short8*)(aptr_c + kf);
        short8 w0 = *(const short8*)(b0p + kf);
        short8 w1 = *(const short8*)(b1p + kf);
        short8 w2 = *(const short8*)(b2p + kf);
        acc0 = __builtin_amdgcn_mfma_f32_16x16x32_bf16(a, w0, acc0, 0, 0, 0);
        acc1 = __builtin_amdgcn_mfma_f32_16x16x32_bf16(a, w1, acc1, 0, 0, 0);
        acc2 = __builtin_amdgcn_mfma_f32_16x16x32_bf16(a, w2, acc2, 0, 0, 0);
    }
    // input half of K (j in [1024,2048))
    #pragma unroll 4
    for (int k0 = 1024; k0 < 2048; k0 += 32) {
        int kf = k0 + kfb;
        short8 a  = *(const short8*)(aptr_x + (kf - 1024));
        short8 w0 = *(const short8*)(b0p + kf);
        short8 w1 = *(const short8*)(b1p + kf);
        short8 w2 = *(const short8*)(b2p + kf);
        acc0 = __builtin_amdgcn_mfma_f32_16x16x32_bf16(a, w0, acc0, 0, 0, 0);
        acc1 = __builtin_amdgcn_mfma_f32_16x16x32_bf16(a, w1, acc1, 0, 0, 0);
        acc2 = __builtin_amdgcn_mfma_f32_16x16x32_bf16(a, w2, acc2, 0, 0, 0);
    }

    // epilogue: lane holds, for rows brow = wv*16 + lkg*4 + r (r=0..3), column u = u0+lrow
    const int u = u0 + lrow;
    const float S0 = S[u],        S1 = S[Uu + u],        S2 = S[2 * Uu + u];
    const float B0 = bias2[u],    B1 = bias2[Uu + u],    B2 = bias2[2 * Uu + u];
    const bool last = (t == Tt - 1);

    #pragma unroll
    for (int r = 0; r < 4; ++r) {
        int brow = wv * 16 + lkg * 4 + r;
        float csx = csums[2 * ((size_t)t * Bb + brow)];
        float csy = csums[2 * ((size_t)t * Bb + brow) + 1];
        float2 xs = xsums[(size_t)brow * Tt + t];
        float mu  = (csx + xs.x) * (1.f / (float)KK);
        float var = (csy + xs.y) * (1.f / (float)KK) - mu * mu;
        float rs  = rsqrtf(var + 1e-3f);
        float mrs = mu * rs;
        float yr = rs * acc0[r] - mrs * S0 + B0;
        float yc = rs * acc1[r] - mrs * S1 + B1;
        float yu = rs * acc2[r] - mrs * S2 + B2;
        float sres = 1.f / (1.f + expf(-yr));
        float cand = tanhf(sres * yc);
        float updv = 1.f / (1.f + expf(-(yu - 1.f)));
        float cold = cf_cur[(size_t)brow * Uu + u];
        float cnew = updv * cand + (1.f - updv) * cold;

        out[(size_t)Bb * Uu + ((size_t)brow * Tt + t) * Uu + u] = cnew;
        if (last) out[(size_t)brow * Uu + u] = cnew;

        float cm = 0.f;
        if (!last) {
            int rr = resets[(size_t)brow * Tt + (t + 1)];
            cm = rr ? 0.f : cnew;
            cf_nxt[(size_t)brow * Uu + u] = cm;
            cb_nxt[(size_t)brow * Uu + u] = f2bf(cm);
        }
        float s = cm, s2 = cm * cm;
        #pragma unroll
        for (int m = 1; m < 16; m <<= 1) {
            s  += __shfl_xor(s,  m, 16);
            s2 += __shfl_xor(s2, m, 16);
        }
        if (!last && lrow == 0) {
            atomicAdd(&csums[2 * ((size_t)(t + 1) * Bb + brow)],     s);
            atomicAdd(&csums[2 * ((size_t)(t + 1) * Bb + brow) + 1], s2);
        }
    }
}

extern "C" void kernel_launch(void* const* d_in, const int* in_sizes, int n_in,
                              void* d_out, int out_size, void* d_ws, size_t ws_size,
                              hipStream_t stream) {
    const float* carry  = (const float*)d_in[0];
    const float* inputs = (const float*)d_in[1];
    const int*   resets = (const int*)d_in[2];
    const float* W      = (const float*)d_in[3];
    const float* bvec   = (const float*)d_in[4];
    const float* lns    = (const float*)d_in[5];
    const float* lnb    = (const float*)d_in[6];
    float* out = (float*)d_out;

    char* ws = (char*)d_ws;
    size_t off = 0;
    auto alloc = [&](size_t bytes) -> void* {
        void* p = ws + off;
        off += (bytes + 255) & ~(size_t)255;
        return p;
    };
    unsigned short* Wsc   = (unsigned short*)alloc((size_t)NN * KK * 2);
    float*          S     = (float*)alloc((size_t)NN * 4);
    float*          bias2 = (float*)alloc((size_t)NN * 4);
    unsigned short* xbf   = (unsigned short*)alloc((size_t)Bb * Tt * Ii * 2);
    float2*         xsums = (float2*)alloc((size_t)Bb * Tt * 8);
    float*          cf    = (float*)alloc((size_t)2 * Bb * Uu * 4);
    unsigned short* cb    = (unsigned short*)alloc((size_t)2 * Bb * Uu * 2);
    float*          csums = (float*)alloc((size_t)(Tt + 1) * Bb * 2 * 4);

    // zero the per-step carry-sum slots (atomically accumulated by step kernels)
    hipMemsetAsync(csums, 0, (size_t)(Tt + 1) * Bb * 2 * 4, stream);

    k_prep_w<<<NN, 256, 0, stream>>>(W, bvec, lns, lnb, Wsc, S, bias2);
    k_prep_x<<<Bb * Tt, 256, 0, stream>>>(inputs, xbf, xsums);
    k_prep_c<<<Bb, 256, 0, stream>>>(carry, resets, cf, cb, csums);

    for (int t = 0; t < Tt; ++t) {
        int cur = t & 1, nxt = cur ^ 1;
        k_step<<<64, 256, 0, stream>>>(
            t, xbf, Wsc, S, bias2, xsums, resets,
            cf + (size_t)cur * Bb * Uu, cb + (size_t)cur * Bb * Uu,
            cf + (size_t)nxt * Bb * Uu, cb + (size_t)nxt * Bb * Uu,
            csums, out);
    }
}

// Round 2
// 12416.177 us; speedup vs baseline: 1.8088x; 1.8088x over previous
//
#include <hip/hip_runtime.h>
#include <stdint.h>

#define Bb 64
#define Tt 512
#define Ii 1024
#define Uu 1024
#define KK 2048
#define NN 3072

typedef __attribute__((ext_vector_type(8))) short short8;
typedef __attribute__((ext_vector_type(4))) float f32x4;

__device__ __forceinline__ unsigned short f2bf(float f) {
    union { float f; unsigned u; } v; v.f = f;
    return (unsigned short)((v.u + 0x7FFFu + ((v.u >> 16) & 1u)) >> 16);
}

// block reduce of two values; valid result only on thread 0
__device__ __forceinline__ float2 block_reduce2(float s, float s2) {
    int lane = threadIdx.x & 63, wv = threadIdx.x >> 6;
    #pragma unroll
    for (int m = 32; m > 0; m >>= 1) {
        s  += __shfl_down(s,  m, 64);
        s2 += __shfl_down(s2, m, 64);
    }
    __shared__ float sh[4][2];
    if (lane == 0) { sh[wv][0] = s; sh[wv][1] = s2; }
    __syncthreads();
    float a = 0.f, b = 0.f;
    if (threadIdx.x == 0) {
        #pragma unroll
        for (int i = 0; i < 4; ++i) { a += sh[i][0]; b += sh[i][1]; }
    }
    return make_float2(a, b);
}

// W (3072x2048 f32) -> Wc bf16 [n][0..1024) (carry cols, scaled), Wx bf16 [n][0..1024) (input cols, scaled),
// S_n = sum_j scale_j*W[n][j] (all 2048), bias2_n = b_n + sum_j lnb_j*W[n][j]
__global__ __launch_bounds__(256) void k_prep_w(
        const float* __restrict__ W, const float* __restrict__ bvec,
        const float* __restrict__ lns, const float* __restrict__ lnb,
        unsigned short* __restrict__ Wc, unsigned short* __restrict__ Wx,
        float* __restrict__ S, float* __restrict__ bias2) {
    int n = blockIdx.x;
    const float* wr = W + (size_t)n * KK;
    float s = 0.f, bb = 0.f;
    for (int j = threadIdx.x; j < KK; j += 256) {
        float w  = wr[j];
        float ws = w * lns[j];
        if (j < Uu) Wc[(size_t)n * Uu + j] = f2bf(ws);
        else        Wx[(size_t)n * Ii + (j - Uu)] = f2bf(ws);
        s  += ws;
        bb += w * lnb[j];
    }
    float2 tot = block_reduce2(s, bb);
    if (threadIdx.x == 0) { S[n] = tot.x; bias2[n] = bvec[n] + tot.y; }
}

// per-(b,t) row sums of f32 inputs; optionally also write bf16 copy (fallback path)
template<bool WRITE_BF>
__global__ __launch_bounds__(256) void k_prep_x(
        const float* __restrict__ X, unsigned short* __restrict__ xbf,
        float2* __restrict__ xsums) {
    size_t row = blockIdx.x;
    const float* xr = X + row * Ii;
    float s = 0.f, s2 = 0.f;
    for (int j = threadIdx.x; j < Ii; j += 256) {
        float v = xr[j];
        if (WRITE_BF) xbf[row * Ii + j] = f2bf(v);
        s += v; s2 += v * v;
    }
    float2 tot = block_reduce2(s, s2);
    if (threadIdx.x == 0) xsums[row] = tot;
}

// initial carry: apply resets[:,0] mask, write f32+bf16 state, write csums slot 0
__global__ __launch_bounds__(256) void k_prep_c(
        const float* __restrict__ carry, const int* __restrict__ resets,
        float* __restrict__ cf, unsigned short* __restrict__ cb,
        float* __restrict__ csums) {
    int b = blockIdx.x;
    int rr = resets[(size_t)b * Tt];
    float s = 0.f, s2 = 0.f;
    for (int u = threadIdx.x; u < Uu; u += 256) {
        float v = rr ? 0.f : carry[(size_t)b * Uu + u];
        cf[(size_t)b * Uu + u] = v;
        cb[(size_t)b * Uu + u] = f2bf(v);
        s += v; s2 += v * v;
    }
    float2 tot = block_reduce2(s, s2);
    if (threadIdx.x == 0) { csums[2 * b] = tot.x; csums[2 * b + 1] = tot.y; }
}

// hoisted input-half GEMM: Gx[m][n] = sum_k bf16(X[m][k]) * Wx[n][k], stored bf16.
// m = b*T + t (32768 rows), n in [0,3072). Block: 64 M x 64 N, 4 waves (one M-subtile each).
__global__ __launch_bounds__(256) void k_gx(
        const float* __restrict__ X, const unsigned short* __restrict__ Wx,
        unsigned short* __restrict__ Gx) {
    const int mb = blockIdx.x;            // 512
    const int nb = blockIdx.y;            // 48
    const int w  = threadIdx.x >> 6;
    const int lane = threadIdx.x & 63;
    const int lrow = lane & 15, lkg = lane >> 4;

    const int mrow = mb * 64 + w * 16 + lrow;
    const float* aP = X + (size_t)mrow * Ii + lkg * 8;
    const int n0 = nb * 64;
    const unsigned short* bP[4];
    #pragma unroll
    for (int c = 0; c < 4; ++c)
        bP[c] = Wx + (size_t)(n0 + c * 16 + lrow) * Ii + lkg * 8;

    f32x4 acc[4] = {{0,0,0,0},{0,0,0,0},{0,0,0,0},{0,0,0,0}};
    #pragma unroll 4
    for (int k0 = 0; k0 < Ii; k0 += 32) {
        float4 alo = *(const float4*)(aP + k0);
        float4 ahi = *(const float4*)(aP + k0 + 4);
        short8 a;
        a[0] = f2bf(alo.x); a[1] = f2bf(alo.y); a[2] = f2bf(alo.z); a[3] = f2bf(alo.w);
        a[4] = f2bf(ahi.x); a[5] = f2bf(ahi.y); a[6] = f2bf(ahi.z); a[7] = f2bf(ahi.w);
        #pragma unroll
        for (int c = 0; c < 4; ++c) {
            short8 bv = *(const short8*)(bP[c] + k0);
            acc[c] = __builtin_amdgcn_mfma_f32_16x16x32_bf16(a, bv, acc[c], 0, 0, 0);
        }
    }
    const int mout = mb * 64 + w * 16 + lkg * 4;
    #pragma unroll
    for (int c = 0; c < 4; ++c)
        #pragma unroll
        for (int r = 0; r < 4; ++r)
            Gx[(size_t)(mout + r) * NN + n0 + c * 16 + lrow] = f2bf(acc[c][r]);
}

// one GRU step. Grid 256 = (batch-tile bt = blockIdx>>6) x (u-tile ut = blockIdx&63).
// 4 waves split K; LDS reduce; epilogue spread across waves (wave w handles acc row r=w).
template<bool FUSED>
__global__ __launch_bounds__(256) void k_step(
        int t,
        const unsigned short* __restrict__ xbf,   // fallback only
        const unsigned short* __restrict__ Gx,    // fused only
        const unsigned short* __restrict__ Wc,
        const unsigned short* __restrict__ Wx,    // fallback only
        const float* __restrict__ S,
        const float* __restrict__ bias2,
        const float2* __restrict__ xsums,
        const int* __restrict__ resets,
        const float* __restrict__ cf_cur,
        const unsigned short* __restrict__ cb_cur,
        float* __restrict__ cf_nxt,
        unsigned short* __restrict__ cb_nxt,
        float* __restrict__ csums,
        float* __restrict__ out) {
    const int ut = blockIdx.x & 63, bt = blockIdx.x >> 6;
    const int u0 = ut * 16;
    const int w  = threadIdx.x >> 6;
    const int lane = threadIdx.x & 63;
    const int lrow = lane & 15, lkg = lane >> 4;
    const bool last = (t == Tt - 1);

    // ---- epilogue operand prefetch (this thread's output element) ----
    const int eR   = lkg * 4 + w;          // row within 16-batch tile
    const int brow = bt * 16 + eR;         // batch row
    const int u    = u0 + lrow;            // output column
    float gx0 = 0.f, gx1 = 0.f, gx2 = 0.f;
    if (FUSED) {
        const unsigned short* gp = Gx + ((size_t)brow * Tt + t) * NN;
        unsigned v0 = gp[u], v1 = gp[Uu + u], v2 = gp[2 * Uu + u];
        union { unsigned u; float f; } c0, c1, c2;
        c0.u = v0 << 16; c1.u = v1 << 16; c2.u = v2 << 16;
        gx0 = c0.f; gx1 = c1.f; gx2 = c2.f;
    }
    const float cold = cf_cur[(size_t)brow * Uu + u];
    const float csx = csums[2 * ((size_t)t * Bb + brow)];
    const float csy = csums[2 * ((size_t)t * Bb + brow) + 1];
    const float2 xs = xsums[(size_t)brow * Tt + t];
    const int rrn = last ? 0 : resets[(size_t)brow * Tt + (t + 1)];

    // ---- K-split GEMM ----
    int kbase, kcount; bool carryHalf;
    if (FUSED) { kbase = w * 256; kcount = 8; carryHalf = true; }
    else {
        if (w < 2) { kbase = w * 512; carryHalf = true; }
        else       { kbase = (w - 2) * 512; carryHalf = false; }
        kcount = 16;
    }
    const int arow = bt * 16 + lrow;
    const unsigned short* ap = (carryHalf ? cb_cur + (size_t)arow * Uu
                                          : xbf + ((size_t)arow * Tt + t) * Ii)
                               + kbase + lkg * 8;
    const unsigned short* WB = carryHalf ? Wc : Wx;
    const unsigned short* b0 = WB + (size_t)(u0 + lrow) * Uu + kbase + lkg * 8;
    const unsigned short* b1 = WB + (size_t)(Uu + u0 + lrow) * Uu + kbase + lkg * 8;
    const unsigned short* b2 = WB + (size_t)(2 * Uu + u0 + lrow) * Uu + kbase + lkg * 8;

    f32x4 acc0 = {0.f, 0.f, 0.f, 0.f};
    f32x4 acc1 = acc0, acc2 = acc0;
    #pragma unroll 4
    for (int i = 0; i < kcount; ++i) {
        int kf = i * 32;
        short8 a  = *(const short8*)(ap + kf);
        short8 w0 = *(const short8*)(b0 + kf);
        short8 w1 = *(const short8*)(b1 + kf);
        short8 w2 = *(const short8*)(b2 + kf);
        acc0 = __builtin_amdgcn_mfma_f32_16x16x32_bf16(a, w0, acc0, 0, 0, 0);
        acc1 = __builtin_amdgcn_mfma_f32_16x16x32_bf16(a, w1, acc1, 0, 0, 0);
        acc2 = __builtin_amdgcn_mfma_f32_16x16x32_bf16(a, w2, acc2, 0, 0, 0);
    }

    // ---- cross-wave K reduction via LDS ----
    __shared__ float sh[4][64][12];   // [wave][lane][gate*4+r] = 12 KiB
    #pragma unroll
    for (int r = 0; r < 4; ++r) {
        sh[w][lane][r]     = acc0[r];
        sh[w][lane][4 + r] = acc1[r];
        sh[w][lane][8 + r] = acc2[r];
    }
    __syncthreads();
    float y0 = 0.f, y1 = 0.f, y2 = 0.f;
    #pragma unroll
    for (int w2 = 0; w2 < 4; ++w2) {
        y0 += sh[w2][lane][w];
        y1 += sh[w2][lane][4 + w];
        y2 += sh[w2][lane][8 + w];
    }

    // ---- LN-linearized epilogue + gates ----
    const float S0 = S[u], S1 = S[Uu + u], S2 = S[2 * Uu + u];
    const float B0 = bias2[u], B1 = bias2[Uu + u], B2 = bias2[2 * Uu + u];
    float mu  = (csx + xs.x) * (1.f / (float)KK);
    float var = (csy + xs.y) * (1.f / (float)KK) - mu * mu;
    float rs  = rsqrtf(var + 1e-3f);
    float mrs = mu * rs;
    float yr = rs * (y0 + gx0) - mrs * S0 + B0;
    float yc = rs * (y1 + gx1) - mrs * S1 + B1;
    float yu = rs * (y2 + gx2) - mrs * S2 + B2;
    float sres = 1.f / (1.f + expf(-yr));
    float cand = tanhf(sres * yc);
    float updv = 1.f / (1.f + expf(-(yu - 1.f)));
    float cnew = updv * cand + (1.f - updv) * cold;

    out[(size_t)Bb * Uu + ((size_t)brow * Tt + t) * Uu + u] = cnew;
    if (last) out[(size_t)brow * Uu + u] = cnew;

    float cm = 0.f;
    if (!last) {
        cm = rrn ? 0.f : cnew;
        cf_nxt[(size_t)brow * Uu + u] = cm;
        cb_nxt[(size_t)brow * Uu + u] = f2bf(cm);
    }
    float s = cm, s2 = cm * cm;
    #pragma unroll
    for (int m = 1; m < 16; m <<= 1) {
        s  += __shfl_xor(s,  m, 16);
        s2 += __shfl_xor(s2, m, 16);
    }
    if (!last && lrow == 0) {
        atomicAdd(&csums[2 * ((size_t)(t + 1) * Bb + brow)],     s);
        atomicAdd(&csums[2 * ((size_t)(t + 1) * Bb + brow) + 1], s2);
    }
}

extern "C" void kernel_launch(void* const* d_in, const int* in_sizes, int n_in,
                              void* d_out, int out_size, void* d_ws, size_t ws_size,
                              hipStream_t stream) {
    const float* carry  = (const float*)d_in[0];
    const float* inputs = (const float*)d_in[1];
    const int*   resets = (const int*)d_in[2];
    const float* W      = (const float*)d_in[3];
    const float* bvec   = (const float*)d_in[4];
    const float* lns    = (const float*)d_in[5];
    const float* lnb    = (const float*)d_in[6];
    float* out = (float*)d_out;

    char* ws = (char*)d_ws;
    size_t off = 0;
    auto alloc = [&](size_t bytes) -> void* {
        void* p = ws + off;
        off += (bytes + 255) & ~(size_t)255;
        return p;
    };
    unsigned short* Wc    = (unsigned short*)alloc((size_t)NN * Uu * 2);
    unsigned short* Wx    = (unsigned short*)alloc((size_t)NN * Ii * 2);
    float*          S     = (float*)alloc((size_t)NN * 4);
    float*          bias2 = (float*)alloc((size_t)NN * 4);
    float2*         xsums = (float2*)alloc((size_t)Bb * Tt * 8);
    float*          cf    = (float*)alloc((size_t)2 * Bb * Uu * 4);
    unsigned short* cb    = (unsigned short*)alloc((size_t)2 * Bb * Uu * 2);
    float*          csums = (float*)alloc((size_t)(Tt + 1) * Bb * 2 * 4);
    size_t base_off = off;
    const size_t gx_bytes  = (size_t)Bb * Tt * NN * 2;  // 201 MB
    const size_t xbf_bytes = (size_t)Bb * Tt * Ii * 2;  // 67 MB
    const bool fused = (ws_size >= base_off + gx_bytes + 256);
    unsigned short* Gx  = nullptr;
    unsigned short* xbf = nullptr;
    if (fused) Gx  = (unsigned short*)alloc(gx_bytes);
    else       xbf = (unsigned short*)alloc(xbf_bytes);

    hipMemsetAsync(csums, 0, (size_t)(Tt + 1) * Bb * 2 * 4, stream);

    k_prep_w<<<NN, 256, 0, stream>>>(W, bvec, lns, lnb, Wc, Wx, S, bias2);
    if (fused) {
        k_prep_x<false><<<Bb * Tt, 256, 0, stream>>>(inputs, nullptr, xsums);
        k_gx<<<dim3(512, 48), 256, 0, stream>>>(inputs, Wx, Gx);
    } else {
        k_prep_x<true><<<Bb * Tt, 256, 0, stream>>>(inputs, xbf, xsums);
    }
    k_prep_c<<<Bb, 256, 0, stream>>>(carry, resets, cf, cb, csums);

    for (int t = 0; t < Tt; ++t) {
        int cur = t & 1, nxt = cur ^ 1;
        if (fused)
            k_step<true><<<256, 256, 0, stream>>>(
                t, nullptr, Gx, Wc, Wx, S, bias2, xsums, resets,
                cf + (size_t)cur * Bb * Uu, cb + (size_t)cur * Bb * Uu,
                cf + (size_t)nxt * Bb * Uu, cb + (size_t)nxt * Bb * Uu,
                csums, out);
        else
            k_step<false><<<256, 256, 0, stream>>>(
                t, xbf, nullptr, Wc, Wx, S, bias2, xsums, resets,
                cf + (size_t)cur * Bb * Uu, cb + (size_t)cur * Bb * Uu,
                cf + (size_t)nxt * Bb * Uu, cb + (size_t)nxt * Bb * Uu,
                csums, out);
    }
}